// Round 1
// baseline (2998.724 us; speedup 1.0000x reference)
//
#include <hip/hip_runtime.h>
#include <math.h>

#define D 128
#define H 256

// ---------------- CSR build ----------------

__global__ __launch_bounds__(256) void k_count(const int* __restrict__ dstA,
                                               int* __restrict__ deg, int E) {
    int e = blockIdx.x * 256 + threadIdx.x;
    if (e < E) atomicAdd(&deg[dstA[e]], 1);
}

__global__ __launch_bounds__(1024) void k_scan(const int* __restrict__ deg,
                                               int* __restrict__ rowptr, int N) {
    __shared__ int sums[1024];
    int t = threadIdx.x;
    int chunk = (N + 1023) >> 10;
    int beg = t * chunk;
    int end = beg + chunk;
    if (end > N) end = N;
    int s = 0;
    for (int i = beg; i < end; ++i) s += deg[i];
    sums[t] = s;
    __syncthreads();
    for (int off = 1; off < 1024; off <<= 1) {
        int v = (t >= off) ? sums[t - off] : 0;
        __syncthreads();
        sums[t] += v;
        __syncthreads();
    }
    int run = (t == 0) ? 0 : sums[t - 1];
    for (int i = beg; i < end; ++i) {
        rowptr[i] = run;
        run += deg[i];
    }
    if (t == 1023) rowptr[N] = sums[1023];
}

__global__ __launch_bounds__(256) void k_scatter(const int* __restrict__ srcA,
                                                 const int* __restrict__ dstA,
                                                 const int* __restrict__ rowptr,
                                                 int* __restrict__ cnt,
                                                 int* __restrict__ srcs, int E) {
    int e = blockIdx.x * 256 + threadIdx.x;
    if (e < E) {
        int d = dstA[e];
        int p = rowptr[d] + atomicAdd(&cnt[d], 1);
        srcs[p] = srcA[e];
    }
}

// ---------------- edge softmax-aggregation (online, single pass) ----------------
// block = 256 threads = 2 nodes x 128 features (2 waves per node).
// g[u][f] = aggr[u][f] + hin[u][f]

__global__ __launch_bounds__(256) void k_edge(const float* __restrict__ hin,
                                              const int* __restrict__ rowptr,
                                              const int* __restrict__ srcs,
                                              const float* __restrict__ tptr,
                                              float* __restrict__ g, int N) {
    int u = blockIdx.x * 2 + (threadIdx.x >> 7);
    if (u >= N) return;
    int f = threadIdx.x & 127;
    float t = *tptr;
    int beg = rowptr[u], end = rowptr[u + 1];
    float m = -__builtin_huge_valf();
    float s = 0.f, sn = 0.f;
    for (int e = beg; e < end; ++e) {
        int v = srcs[e];
        float val = fmaxf(hin[v * D + f], 0.f) + 1e-7f;
        float lg = val * t;
        float nm = fmaxf(m, lg);
        float a = __expf(m - nm);   // exp(-inf)=0 on first edge
        float w = __expf(lg - nm);
        s = s * a + w;
        sn = sn * a + w * val;
        m = nm;
    }
    float aggr = sn / (s + 1e-16f);  // empty segment: 0/(1e-16)=0, matches ref
    g[u * D + f] = aggr + hin[u * D + f];
}

// ---------------- mm1: h1 = g @ W1, fused BN column sum/sumsq partials ----------------
// 64x64 tile, 256 threads, 4x4 micro-tile. K = 128 (full, LDS-resident).

__global__ __launch_bounds__(256) void k_mm1(const float* __restrict__ A,
                                             const float* __restrict__ W,
                                             float* __restrict__ C,
                                             float* __restrict__ bnsum,
                                             float* __restrict__ bnss, int M) {
    __shared__ float As[64][132];   // +4 pad: break bank aliasing, keep 16B align
    __shared__ float Bs[128][64];
    __shared__ float csum[64], css[64];
    int row0 = blockIdx.x * 64, col0 = blockIdx.y * 64;
    int tid = threadIdx.x;

    #pragma unroll
    for (int it = 0; it < 32; ++it) {
        int idx = it * 256 + tid;
        int r = idx >> 7, k = idx & 127;
        int rr = row0 + r;
        As[r][k] = (rr < M) ? A[rr * D + k] : 0.f;
    }
    #pragma unroll
    for (int it = 0; it < 32; ++it) {
        int idx = it * 256 + tid;
        int k = idx >> 6, c = idx & 63;
        Bs[k][c] = W[k * H + col0 + c];
    }
    if (tid < 64) { csum[tid] = 0.f; css[tid] = 0.f; }
    __syncthreads();

    int tx = tid & 15, ty = tid >> 4;
    float acc[4][4];
    #pragma unroll
    for (int r = 0; r < 4; ++r)
        #pragma unroll
        for (int j = 0; j < 4; ++j) acc[r][j] = 0.f;

    #pragma unroll 4
    for (int k = 0; k < 128; k += 4) {
        float4 b0 = *(const float4*)(&Bs[k + 0][tx * 4]);
        float4 b1 = *(const float4*)(&Bs[k + 1][tx * 4]);
        float4 b2 = *(const float4*)(&Bs[k + 2][tx * 4]);
        float4 b3 = *(const float4*)(&Bs[k + 3][tx * 4]);
        #pragma unroll
        for (int r = 0; r < 4; ++r) {
            float4 a = *(const float4*)(&As[ty * 4 + r][k]);
            acc[r][0] += a.x * b0.x + a.y * b1.x + a.z * b2.x + a.w * b3.x;
            acc[r][1] += a.x * b0.y + a.y * b1.y + a.z * b2.y + a.w * b3.y;
            acc[r][2] += a.x * b0.z + a.y * b1.z + a.z * b2.z + a.w * b3.z;
            acc[r][3] += a.x * b0.w + a.y * b1.w + a.z * b2.w + a.w * b3.w;
        }
    }

    // BN partials (OOB rows contribute exact 0 since As was zero-filled)
    #pragma unroll
    for (int j = 0; j < 4; ++j) {
        float s = 0.f, ss = 0.f;
        #pragma unroll
        for (int r = 0; r < 4; ++r) {
            float v = acc[r][j];
            s += v;
            ss += v * v;
        }
        atomicAdd(&csum[tx * 4 + j], s);
        atomicAdd(&css[tx * 4 + j], ss);
    }
    // store C
    #pragma unroll
    for (int r = 0; r < 4; ++r) {
        int rr = row0 + ty * 4 + r;
        if (rr < M) {
            float4 v = make_float4(acc[r][0], acc[r][1], acc[r][2], acc[r][3]);
            *(float4*)(&C[rr * H + col0 + tx * 4]) = v;
        }
    }
    __syncthreads();
    if (tid < 64) {
        atomicAdd(&bnsum[col0 + tid], csum[tid]);
        atomicAdd(&bnss[col0 + tid], css[tid]);
    }
}

// ---------------- BN finalize: scale/shift per column ----------------

__global__ __launch_bounds__(256) void k_bnfin(const float* __restrict__ bnsum,
                                               const float* __restrict__ bnss,
                                               const float* __restrict__ gamma,
                                               const float* __restrict__ beta,
                                               float* __restrict__ scale,
                                               float* __restrict__ shift, int M) {
    int c = threadIdx.x;
    float inv = 1.0f / (float)M;
    float mean = bnsum[c] * inv;
    float var = bnss[c] * inv - mean * mean;
    if (var < 0.f) var = 0.f;
    float rstd = rsqrtf(var + 1e-5f);
    float sc = rstd * gamma[c];
    scale[c] = sc;
    shift[c] = beta[c] - mean * sc;
}

// ---------------- mm2: out = relu(h1*scale+shift) @ W2 (norm fused in A-load) ----------------
// 64x64 tile, K = 256 in two 128-chunks.

__global__ __launch_bounds__(256) void k_mm2(const float* __restrict__ H1,
                                             const float* __restrict__ scale,
                                             const float* __restrict__ shift,
                                             const float* __restrict__ W,
                                             float* __restrict__ C, int M,
                                             int relu_out) {
    __shared__ float As[64][132];
    __shared__ float Bs[128][64];
    int row0 = blockIdx.x * 64, col0 = blockIdx.y * 64;
    int tid = threadIdx.x;
    int tx = tid & 15, ty = tid >> 4;
    float acc[4][4];
    #pragma unroll
    for (int r = 0; r < 4; ++r)
        #pragma unroll
        for (int j = 0; j < 4; ++j) acc[r][j] = 0.f;

    for (int kk = 0; kk < H; kk += 128) {
        #pragma unroll
        for (int it = 0; it < 32; ++it) {
            int idx = it * 256 + tid;
            int r = idx >> 7, k = idx & 127;
            int rr = row0 + r;
            int kg = kk + k;
            float v = 0.f;
            if (rr < M) v = fmaxf(H1[rr * H + kg] * scale[kg] + shift[kg], 0.f);
            As[r][k] = v;
        }
        #pragma unroll
        for (int it = 0; it < 32; ++it) {
            int idx = it * 256 + tid;
            int k = idx >> 6, c = idx & 63;
            Bs[k][c] = W[(kk + k) * D + col0 + c];
        }
        __syncthreads();
        #pragma unroll 4
        for (int k = 0; k < 128; k += 4) {
            float4 b0 = *(const float4*)(&Bs[k + 0][tx * 4]);
            float4 b1 = *(const float4*)(&Bs[k + 1][tx * 4]);
            float4 b2 = *(const float4*)(&Bs[k + 2][tx * 4]);
            float4 b3 = *(const float4*)(&Bs[k + 3][tx * 4]);
            #pragma unroll
            for (int r = 0; r < 4; ++r) {
                float4 a = *(const float4*)(&As[ty * 4 + r][k]);
                acc[r][0] += a.x * b0.x + a.y * b1.x + a.z * b2.x + a.w * b3.x;
                acc[r][1] += a.x * b0.y + a.y * b1.y + a.z * b2.y + a.w * b3.y;
                acc[r][2] += a.x * b0.z + a.y * b1.z + a.z * b2.z + a.w * b3.z;
                acc[r][3] += a.x * b0.w + a.y * b1.w + a.z * b2.w + a.w * b3.w;
            }
        }
        __syncthreads();
    }

    #pragma unroll
    for (int r = 0; r < 4; ++r) {
        int rr = row0 + ty * 4 + r;
        if (rr < M) {
            float4 v = make_float4(acc[r][0], acc[r][1], acc[r][2], acc[r][3]);
            if (relu_out) {
                v.x = fmaxf(v.x, 0.f); v.y = fmaxf(v.y, 0.f);
                v.z = fmaxf(v.z, 0.f); v.w = fmaxf(v.w, 0.f);
            }
            *(float4*)(&C[rr * D + col0 + tx * 4]) = v;
        }
    }
}

// ---------------- host launch ----------------

extern "C" void kernel_launch(void* const* d_in, const int* in_sizes, int n_in,
                              void* d_out, int out_size, void* d_ws, size_t ws_size,
                              hipStream_t stream) {
    const float* x         = (const float*)d_in[0];
    const int*   ei        = (const int*)d_in[1];
    const float* t_all     = (const float*)d_in[2];
    const float* W1_all    = (const float*)d_in[3];
    const float* W2_all    = (const float*)d_in[4];
    const float* gamma_all = (const float*)d_in[5];
    const float* beta_all  = (const float*)d_in[6];

    int N = in_sizes[0] / D;
    int E = in_sizes[1] / 2;
    float* out = (float*)d_out;

    char* ws = (char*)d_ws;
    size_t off = 0;
    auto alloc = [&](size_t bytes) -> void* {
        void* p = ws + off;
        off += (bytes + 255) & ~(size_t)255;
        return p;
    };
    int*   rowptr = (int*)alloc((size_t)(N + 1) * 4);
    int*   deg    = (int*)alloc((size_t)N * 4);       // also scatter counter
    int*   srcs   = (int*)alloc((size_t)E * 4);
    float* g      = (float*)alloc((size_t)N * D * 4);
    float* h1     = (float*)alloc((size_t)N * H * 4);
    float* bnsum  = (float*)alloc(H * 4);
    float* bnss   = (float*)alloc(H * 4);
    float* scale  = (float*)alloc(H * 4);
    float* shift  = (float*)alloc(H * 4);
    (void)ws_size; (void)n_in; (void)out_size;

    const int* srcA = ei;
    const int* dstA = ei + E;

    // CSR build (once; shared by all 4 layers)
    hipMemsetAsync(deg, 0, (size_t)N * 4, stream);
    k_count<<<(E + 255) / 256, 256, 0, stream>>>(dstA, deg, E);
    k_scan<<<1, 1024, 0, stream>>>(deg, rowptr, N);
    hipMemsetAsync(deg, 0, (size_t)N * 4, stream);
    k_scatter<<<(E + 255) / 256, 256, 0, stream>>>(srcA, dstA, rowptr, deg, srcs, E);

    // layer activations live in the two halves of d_out (overwritten at the end
    // by mu / logstd):
    float* out0 = out;                     // mu region
    float* out1 = out + (size_t)N * D;     // logstd region

    const float* hin = x;
    for (int layer = 0; layer < 4; ++layer) {
        k_edge<<<(N + 1) / 2, 256, 0, stream>>>(hin, rowptr, srcs, t_all + layer, g, N);

        hipMemsetAsync(bnsum, 0, H * 4, stream);
        hipMemsetAsync(bnss, 0, H * 4, stream);
        k_mm1<<<dim3((N + 63) / 64, H / 64), 256, 0, stream>>>(
            g, W1_all + (size_t)layer * D * H, h1, bnsum, bnss, N);
        k_bnfin<<<1, H, 0, stream>>>(bnsum, bnss, gamma_all + (size_t)layer * H,
                                     beta_all + (size_t)layer * H, scale, shift, N);

        float* outp;
        int relu_out;
        if (layer == 0)      { outp = out0; relu_out = 1; }
        else if (layer == 1) { outp = out1; relu_out = 1; }
        else if (layer == 2) { outp = out0; relu_out = 0; }  // mu
        else                 { outp = out1; relu_out = 0; }  // logstd

        k_mm2<<<dim3((N + 63) / 64, D / 64), 256, 0, stream>>>(
            h1, scale, shift, W2_all + (size_t)layer * H * D, outp, N, relu_out);

        // L0 -> out0, L1 -> out1; layers 2 & 3 both read out1 (written by L1).
        // L2 writes out0 (mu) without clobbering out1; L3 consumes out1 in its
        // edge phase before mm2 overwrites it with logstd.
        hin = (layer == 0) ? out0 : out1;
    }
}

// Round 4
// 1495.052 us; speedup vs baseline: 2.0058x; 2.0058x over previous
//
#include <hip/hip_runtime.h>
#include <math.h>

#define D 128
#define H 256

typedef short s16x8 __attribute__((ext_vector_type(8)));  // 8 bf16 bit-patterns (4 VGPRs)
typedef float f32x4 __attribute__((ext_vector_type(4)));
typedef unsigned short u16;

// float -> bf16 (round-nearest-even) as bit pattern
__device__ __forceinline__ u16 f2b(float f) {
    union { float f; unsigned u; } c;
    c.f = f;
    unsigned u = c.u + 0x7FFFu + ((c.u >> 16) & 1u);
    return (u16)(u >> 16);
}
__device__ __forceinline__ float b2f(u16 h) {
    union { unsigned u; float f; } c;
    c.u = ((unsigned)h) << 16;
    return c.f;
}

// ---------------- CSR build ----------------

__global__ __launch_bounds__(256) void k_count(const int* __restrict__ dstA,
                                               int* __restrict__ deg, int E) {
    int e = blockIdx.x * 256 + threadIdx.x;
    if (e < E) atomicAdd(&deg[dstA[e]], 1);
}

__global__ __launch_bounds__(1024) void k_scan(const int* __restrict__ deg,
                                               int* __restrict__ rowptr, int N) {
    __shared__ int sums[1024];
    int t = threadIdx.x;
    int chunk = (N + 1023) >> 10;
    int beg = t * chunk;
    int end = beg + chunk;
    if (end > N) end = N;
    int s = 0;
    for (int i = beg; i < end; ++i) s += deg[i];
    sums[t] = s;
    __syncthreads();
    for (int off = 1; off < 1024; off <<= 1) {
        int v = (t >= off) ? sums[t - off] : 0;
        __syncthreads();
        sums[t] += v;
        __syncthreads();
    }
    int run = (t == 0) ? 0 : sums[t - 1];
    for (int i = beg; i < end; ++i) {
        rowptr[i] = run;
        run += deg[i];
    }
    if (t == 1023) rowptr[N] = sums[1023];
}

__global__ __launch_bounds__(256) void k_scatter(const int* __restrict__ srcA,
                                                 const int* __restrict__ dstA,
                                                 const int* __restrict__ rowptr,
                                                 int* __restrict__ cnt,
                                                 int* __restrict__ srcs, int E) {
    int e = blockIdx.x * 256 + threadIdx.x;
    if (e < E) {
        int d = dstA[e];
        int p = rowptr[d] + atomicAdd(&cnt[d], 1);
        srcs[p] = srcA[e];
    }
}

// ---------------- prep: fp32 -> bf16 casts & weight transpose ----------------

__global__ __launch_bounds__(256) void k_cvt(const float* __restrict__ x,
                                             u16* __restrict__ xb, int n4) {
    int i = blockIdx.x * 256 + threadIdx.x;
    if (i < n4) {
        float4 v = ((const float4*)x)[i];
        xb[i * 4 + 0] = f2b(v.x);
        xb[i * 4 + 1] = f2b(v.y);
        xb[i * 4 + 2] = f2b(v.z);
        xb[i * 4 + 3] = f2b(v.w);
    }
}

// WT1[l][n(256)][k(128)] = W1[l][k][n];  WT2[l][n(128)][k(256)] = W2[l][k][n]
__global__ __launch_bounds__(256) void k_prep(const float* __restrict__ W1_all,
                                              const float* __restrict__ W2_all,
                                              u16* __restrict__ WT1,
                                              u16* __restrict__ WT2) {
    int id = blockIdx.x * 256 + threadIdx.x;   // 262144 total
    if (id < 131072) {
        int l = id >> 15, rem = id & 32767, n = rem >> 7, k = rem & 127;
        WT1[id] = f2b(W1_all[l * 32768 + k * 256 + n]);
    } else {
        int id2 = id - 131072;
        int l = id2 >> 15, rem = id2 & 32767, n = rem >> 8, k = rem & 255;
        WT2[id2] = f2b(W2_all[l * 32768 + k * 128 + n]);
    }
}

// ---------------- edge softmax-aggregation (online, single pass) ----------------
// bf16 in (gather), bf16 out. block = 256 = 2 nodes x 128 features.

__global__ __launch_bounds__(256) void k_edge(const u16* __restrict__ hin,
                                              const int* __restrict__ rowptr,
                                              const int* __restrict__ srcs,
                                              const float* __restrict__ tptr,
                                              u16* __restrict__ g, int N) {
    int u = blockIdx.x * 2 + (threadIdx.x >> 7);
    if (u >= N) return;
    int f = threadIdx.x & 127;
    float t = *tptr;
    int beg = rowptr[u], end = rowptr[u + 1];
    float m = -__builtin_huge_valf();
    float s = 0.f, sn = 0.f;
    for (int e = beg; e < end; ++e) {
        int v = srcs[e];
        float val = fmaxf(b2f(hin[(size_t)v * D + f]), 0.f) + 1e-7f;
        float lg = val * t;
        float nm = fmaxf(m, lg);
        float a = __expf(m - nm);
        float w = __expf(lg - nm);
        s = s * a + w;
        sn = sn * a + w * val;
        m = nm;
    }
    float aggr = sn / (s + 1e-16f);
    float hv = b2f(hin[(size_t)u * D + f]);
    g[(size_t)u * D + f] = f2b(aggr + hv);
}

// ---------------- mm1: h1 = g @ W1 (bf16 MFMA), fused BN partials ----------------
// 128x128 tile, 256 threads (4 waves), BK=64 chunks, K=128.
// A: g bf16 [M x 128]; B: WT1 bf16 [n(256) x k(128)] (n-major).

__global__ __launch_bounds__(256) void k_mm1(const u16* __restrict__ A,
                                             const u16* __restrict__ WT,
                                             u16* __restrict__ C,
                                             float* __restrict__ bnsum,
                                             float* __restrict__ bnss, int M) {
    __shared__ u16 As[128][72];   // stride 144B: 2-way bank alias (free)
    __shared__ u16 Bs[128][72];
    __shared__ float csum[128], css[128];
    int row0 = blockIdx.x * 128, n0 = blockIdx.y * 128;
    int tid = threadIdx.x;
    int lane = tid & 63, w = tid >> 6;
    int r0w = (w & 1) * 64, c0w = (w >> 1) * 64;
    int q = lane >> 4, ml = lane & 15;

    if (tid < 128) { csum[tid] = 0.f; css[tid] = 0.f; }

    f32x4 acc[4][4];
    #pragma unroll
    for (int i = 0; i < 4; ++i)
        #pragma unroll
        for (int j = 0; j < 4; ++j) acc[i][j] = f32x4{0.f, 0.f, 0.f, 0.f};

    for (int kk = 0; kk < 128; kk += 64) {
        // stage: 8192 els each, 32 els/thread
        #pragma unroll
        for (int i = 0; i < 4; ++i) {
            int r = i * 32 + (tid >> 3);
            int c8 = (tid & 7) * 8;
            s16x8 va = s16x8{0, 0, 0, 0, 0, 0, 0, 0};
            if (row0 + r < M)
                va = *reinterpret_cast<const s16x8*>(&A[(size_t)(row0 + r) * 128 + kk + c8]);
            *reinterpret_cast<s16x8*>(&As[r][c8]) = va;
            s16x8 vb = *reinterpret_cast<const s16x8*>(&WT[(size_t)(n0 + r) * 128 + kk + c8]);
            *reinterpret_cast<s16x8*>(&Bs[r][c8]) = vb;
        }
        __syncthreads();
        #pragma unroll
        for (int ks = 0; ks < 64; ks += 32) {
            s16x8 af[4], bfr[4];
            #pragma unroll
            for (int rt = 0; rt < 4; ++rt)
                af[rt] = *reinterpret_cast<const s16x8*>(&As[r0w + rt * 16 + ml][ks + q * 8]);
            #pragma unroll
            for (int ct = 0; ct < 4; ++ct)
                bfr[ct] = *reinterpret_cast<const s16x8*>(&Bs[c0w + ct * 16 + ml][ks + q * 8]);
            #pragma unroll
            for (int rt = 0; rt < 4; ++rt)
                #pragma unroll
                for (int ct = 0; ct < 4; ++ct)
                    acc[rt][ct] = __builtin_amdgcn_mfma_f32_16x16x32_bf16(
                        af[rt], bfr[ct], acc[rt][ct], 0, 0, 0);
        }
        __syncthreads();
    }

    // epilogue: store bf16 h1 + BN partial sums
    #pragma unroll
    for (int ct = 0; ct < 4; ++ct) {
        float s = 0.f, ss = 0.f;
        int col = n0 + c0w + ct * 16 + ml;
        #pragma unroll
        for (int rt = 0; rt < 4; ++rt) {
            int rbase = row0 + r0w + rt * 16 + q * 4;
            #pragma unroll
            for (int rg = 0; rg < 4; ++rg) {
                float v = acc[rt][ct][rg];
                s += v;
                ss += v * v;
                if (rbase + rg < M)
                    C[(size_t)(rbase + rg) * H + col] = f2b(v);
            }
        }
        atomicAdd(&csum[c0w + ct * 16 + ml], s);
        atomicAdd(&css[c0w + ct * 16 + ml], ss);
    }
    __syncthreads();
    if (tid < 128) {
        atomicAdd(&bnsum[n0 + tid], csum[tid]);
        atomicAdd(&bnss[n0 + tid], css[tid]);
    }
}

// ---------------- BN finalize ----------------

__global__ __launch_bounds__(256) void k_bnfin(const float* __restrict__ bnsum,
                                               const float* __restrict__ bnss,
                                               const float* __restrict__ gamma,
                                               const float* __restrict__ beta,
                                               float* __restrict__ scale,
                                               float* __restrict__ shift, int M) {
    int c = threadIdx.x;
    float inv = 1.0f / (float)M;
    float mean = bnsum[c] * inv;
    float var = bnss[c] * inv - mean * mean;
    if (var < 0.f) var = 0.f;
    float rstd = rsqrtf(var + 1e-5f);
    float sc = rstd * gamma[c];
    scale[c] = sc;
    shift[c] = beta[c] - mean * sc;
}

// ---------------- mm2: out = relu(norm(h1)) @ W2 (norm fused in A-stage) ----------------
// K=256 in 4 BK=64 chunks. Output: fp32 (mu/logstd) or bf16+relu (hidden acts).

__global__ __launch_bounds__(256) void k_mm2(const u16* __restrict__ H1,
                                             const float* __restrict__ scale,
                                             const float* __restrict__ shift,
                                             const u16* __restrict__ WT,
                                             float* __restrict__ outf,
                                             u16* __restrict__ outb, int M) {
    __shared__ u16 As[128][72];
    __shared__ u16 Bs[128][72];
    int row0 = blockIdx.x * 128;
    int tid = threadIdx.x;
    int lane = tid & 63, w = tid >> 6;
    int r0w = (w & 1) * 64, c0w = (w >> 1) * 64;
    int q = lane >> 4, ml = lane & 15;

    f32x4 acc[4][4];
    #pragma unroll
    for (int i = 0; i < 4; ++i)
        #pragma unroll
        for (int j = 0; j < 4; ++j) acc[i][j] = f32x4{0.f, 0.f, 0.f, 0.f};

    for (int kk = 0; kk < 256; kk += 64) {
        #pragma unroll
        for (int i = 0; i < 4; ++i) {
            int r = i * 32 + (tid >> 3);
            int c8 = (tid & 7) * 8;
            s16x8 o = s16x8{0, 0, 0, 0, 0, 0, 0, 0};
            if (row0 + r < M) {
                s16x8 v = *reinterpret_cast<const s16x8*>(&H1[(size_t)(row0 + r) * H + kk + c8]);
                #pragma unroll
                for (int j = 0; j < 8; ++j) {
                    float f = b2f((u16)v[j]) * scale[kk + c8 + j] + shift[kk + c8 + j];
                    o[j] = (short)f2b(fmaxf(f, 0.f));
                }
            }
            *reinterpret_cast<s16x8*>(&As[r][c8]) = o;
            s16x8 vb = *reinterpret_cast<const s16x8*>(&WT[(size_t)r * H + kk + c8]);
            *reinterpret_cast<s16x8*>(&Bs[r][c8]) = vb;
        }
        __syncthreads();
        #pragma unroll
        for (int ks = 0; ks < 64; ks += 32) {
            s16x8 af[4], bfr[4];
            #pragma unroll
            for (int rt = 0; rt < 4; ++rt)
                af[rt] = *reinterpret_cast<const s16x8*>(&As[r0w + rt * 16 + ml][ks + q * 8]);
            #pragma unroll
            for (int ct = 0; ct < 4; ++ct)
                bfr[ct] = *reinterpret_cast<const s16x8*>(&Bs[c0w + ct * 16 + ml][ks + q * 8]);
            #pragma unroll
            for (int rt = 0; rt < 4; ++rt)
                #pragma unroll
                for (int ct = 0; ct < 4; ++ct)
                    acc[rt][ct] = __builtin_amdgcn_mfma_f32_16x16x32_bf16(
                        af[rt], bfr[ct], acc[rt][ct], 0, 0, 0);
        }
        __syncthreads();
    }

    #pragma unroll
    for (int ct = 0; ct < 4; ++ct) {
        int col = c0w + ct * 16 + ml;
        #pragma unroll
        for (int rt = 0; rt < 4; ++rt) {
            int rbase = row0 + r0w + rt * 16 + q * 4;
            #pragma unroll
            for (int rg = 0; rg < 4; ++rg) {
                if (rbase + rg < M) {
                    float v = acc[rt][ct][rg];
                    if (outb)
                        outb[(size_t)(rbase + rg) * D + col] = f2b(fmaxf(v, 0.f));
                    else
                        outf[(size_t)(rbase + rg) * D + col] = v;
                }
            }
        }
    }
}

// ---------------- host launch ----------------

extern "C" void kernel_launch(void* const* d_in, const int* in_sizes, int n_in,
                              void* d_out, int out_size, void* d_ws, size_t ws_size,
                              hipStream_t stream) {
    const float* x         = (const float*)d_in[0];
    const int*   ei        = (const int*)d_in[1];
    const float* t_all     = (const float*)d_in[2];
    const float* W1_all    = (const float*)d_in[3];
    const float* W2_all    = (const float*)d_in[4];
    const float* gamma_all = (const float*)d_in[5];
    const float* beta_all  = (const float*)d_in[6];

    int N = in_sizes[0] / D;
    int E = in_sizes[1] / 2;
    float* out = (float*)d_out;

    char* ws = (char*)d_ws;
    size_t off = 0;
    auto alloc = [&](size_t bytes) -> void* {
        void* p = ws + off;
        off += (bytes + 255) & ~(size_t)255;
        return p;
    };
    int* rowptr = (int*)alloc((size_t)(N + 1) * 4);
    int* deg    = (int*)alloc((size_t)N * 4);
    int* srcs   = (int*)alloc((size_t)E * 4);
    u16* xb     = (u16*)alloc((size_t)N * D * 2);
    u16* a0     = (u16*)alloc((size_t)N * D * 2);
    u16* a1     = (u16*)alloc((size_t)N * D * 2);
    u16* g      = (u16*)alloc((size_t)N * D * 2);
    u16* h1     = (u16*)alloc((size_t)N * H * 2);
    u16* WT1    = (u16*)alloc((size_t)4 * H * D * 2);
    u16* WT2    = (u16*)alloc((size_t)4 * D * H * 2);
    float* bnsum = (float*)alloc(H * 4);
    float* bnss  = (float*)alloc(H * 4);
    float* scale = (float*)alloc(H * 4);
    float* shift = (float*)alloc(H * 4);
    (void)ws_size; (void)n_in; (void)out_size;

    const int* srcA = ei;
    const int* dstA = ei + E;

    // prep: bf16 casts + weight transposes
    k_cvt<<<(N * D / 4 + 255) / 256, 256, 0, stream>>>(x, xb, N * D / 4);
    k_prep<<<1024, 256, 0, stream>>>(W1_all, W2_all, WT1, WT2);

    // CSR build
    hipMemsetAsync(deg, 0, (size_t)N * 4, stream);
    k_count<<<(E + 255) / 256, 256, 0, stream>>>(dstA, deg, E);
    k_scan<<<1, 1024, 0, stream>>>(deg, rowptr, N);
    hipMemsetAsync(deg, 0, (size_t)N * 4, stream);
    k_scatter<<<(E + 255) / 256, 256, 0, stream>>>(srcA, dstA, rowptr, deg, srcs, E);

    float* out0 = out;                  // mu
    float* out1 = out + (size_t)N * D;  // logstd

    int gx = (N + 127) / 128;
    for (int layer = 0; layer < 4; ++layer) {
        const u16* hin = (layer == 0) ? xb : (layer == 1 ? a0 : a1);
        k_edge<<<(N + 1) / 2, 256, 0, stream>>>(hin, rowptr, srcs, t_all + layer, g, N);

        hipMemsetAsync(bnsum, 0, H * 4, stream);
        hipMemsetAsync(bnss, 0, H * 4, stream);
        k_mm1<<<dim3(gx, 2), 256, 0, stream>>>(g, WT1 + (size_t)layer * H * D, h1,
                                               bnsum, bnss, N);
        k_bnfin<<<1, H, 0, stream>>>(bnsum, bnss, gamma_all + (size_t)layer * H,
                                     beta_all + (size_t)layer * H, scale, shift, N);

        float* outf = nullptr;
        u16*   outb = nullptr;
        if (layer == 0)      outb = a0;
        else if (layer == 1) outb = a1;
        else if (layer == 2) outf = out0;
        else                 outf = out1;

        k_mm2<<<dim3(gx, 1), 256, 0, stream>>>(h1, scale, shift,
                                               WT2 + (size_t)layer * D * H,
                                               outf, outb, N);
    }
}

// Round 5
// 1180.127 us; speedup vs baseline: 2.5410x; 1.2669x over previous
//
#include <hip/hip_runtime.h>
#include <math.h>

#define D 128
#define H 256

typedef short s16x8 __attribute__((ext_vector_type(8)));  // 8 bf16 bit-patterns (4 VGPRs)
typedef float f32x4 __attribute__((ext_vector_type(4)));
typedef unsigned short u16;
typedef unsigned int u32;

// float -> bf16 (round-nearest-even) as bit pattern
__device__ __forceinline__ u16 f2b(float f) {
    union { float f; unsigned u; } c;
    c.f = f;
    unsigned u = c.u + 0x7FFFu + ((c.u >> 16) & 1u);
    return (u16)(u >> 16);
}
__device__ __forceinline__ float b2f(u16 h) {
    union { unsigned u; float f; } c;
    c.u = ((unsigned)h) << 16;
    return c.f;
}
__device__ __forceinline__ float blo(u32 p) {   // bf16 in low half
    union { unsigned u; float f; } c;
    c.u = p << 16;
    return c.f;
}
__device__ __forceinline__ float bhi(u32 p) {   // bf16 in high half
    union { unsigned u; float f; } c;
    c.u = p & 0xFFFF0000u;
    return c.f;
}

// ---------------- CSR build ----------------

__global__ __launch_bounds__(256) void k_count(const int* __restrict__ dstA,
                                               int* __restrict__ deg, int E) {
    int e = blockIdx.x * 256 + threadIdx.x;
    if (e < E) atomicAdd(&deg[dstA[e]], 1);
}

__global__ __launch_bounds__(1024) void k_scan(const int* __restrict__ deg,
                                               int* __restrict__ rowptr, int N) {
    __shared__ int sums[1024];
    int t = threadIdx.x;
    int chunk = (N + 1023) >> 10;
    int beg = t * chunk;
    int end = beg + chunk;
    if (end > N) end = N;
    int s = 0;
    for (int i = beg; i < end; ++i) s += deg[i];
    sums[t] = s;
    __syncthreads();
    for (int off = 1; off < 1024; off <<= 1) {
        int v = (t >= off) ? sums[t - off] : 0;
        __syncthreads();
        sums[t] += v;
        __syncthreads();
    }
    int run = (t == 0) ? 0 : sums[t - 1];
    for (int i = beg; i < end; ++i) {
        rowptr[i] = run;
        run += deg[i];
    }
    if (t == 1023) rowptr[N] = sums[1023];
}

__global__ __launch_bounds__(256) void k_scatter(const int* __restrict__ srcA,
                                                 const int* __restrict__ dstA,
                                                 const int* __restrict__ rowptr,
                                                 int* __restrict__ cnt,
                                                 int* __restrict__ srcs, int E) {
    int e = blockIdx.x * 256 + threadIdx.x;
    if (e < E) {
        int d = dstA[e];
        int p = rowptr[d] + atomicAdd(&cnt[d], 1);
        srcs[p] = srcA[e];
    }
}

// ---------------- prep: fp32 -> bf16 casts & weight transpose ----------------

__global__ __launch_bounds__(256) void k_cvt(const float* __restrict__ x,
                                             u16* __restrict__ xb, int n4) {
    int i = blockIdx.x * 256 + threadIdx.x;
    if (i < n4) {
        float4 v = ((const float4*)x)[i];
        xb[i * 4 + 0] = f2b(v.x);
        xb[i * 4 + 1] = f2b(v.y);
        xb[i * 4 + 2] = f2b(v.z);
        xb[i * 4 + 3] = f2b(v.w);
    }
}

// WT1[l][n(256)][k(128)] = W1[l][k][n];  WT2[l][n(128)][k(256)] = W2[l][k][n]
__global__ __launch_bounds__(256) void k_prep(const float* __restrict__ W1_all,
                                              const float* __restrict__ W2_all,
                                              u16* __restrict__ WT1,
                                              u16* __restrict__ WT2) {
    int id = blockIdx.x * 256 + threadIdx.x;   // 262144 total
    if (id < 131072) {
        int l = id >> 15, rem = id & 32767, n = rem >> 7, k = rem & 127;
        WT1[id] = f2b(W1_all[l * 32768 + k * 256 + n]);
    } else {
        int id2 = id - 131072;
        int l = id2 >> 15, rem = id2 & 32767, n = rem >> 8, k = rem & 255;
        WT2[id2] = f2b(W2_all[l * 32768 + k * 128 + n]);
    }
}

// ---------------- edge softmax-aggregation ----------------
// One wave per node; lane handles features {2*lane, 2*lane+1} via one u32 load.
// Fast path: no max-rescale (exps independent across iterations -> ILP);
// exact-online fallback voted per wave (never taken for sane t/activations).
// Also zeroes the BN accumulators (block 0) to save two memset dispatches.

__global__ __launch_bounds__(256) void k_edge(const u16* __restrict__ hin,
                                              const int* __restrict__ rowptr,
                                              const int* __restrict__ srcs,
                                              const float* __restrict__ tptr,
                                              u16* __restrict__ g,
                                              float* __restrict__ bnsum,
                                              float* __restrict__ bnss, int N) {
    if (blockIdx.x == 0) {       // zero BN partial buffers for this layer's mm1
        bnsum[threadIdx.x] = 0.f;
        bnss[threadIdx.x] = 0.f;
    }
    int u = blockIdx.x * 4 + (threadIdx.x >> 6);
    if (u >= N) return;
    int lane = threadIdx.x & 63;
    const u32* hin32 = (const u32*)hin;
    float t = *tptr;
    int beg = rowptr[u], end = rowptr[u + 1];

    float s0 = 0.f, s1 = 0.f, sn0 = 0.f, sn1 = 0.f;
    float mx = -3.0e38f, mv = 0.f;

    // software-pipelined fast path: prefetch next (src, row) before processing
    if (beg < end) {
        int v = srcs[beg];
        u32 p = hin32[(size_t)v * 64 + lane];
        for (int e = beg; e < end; ++e) {
            int en = e + 1 < end ? e + 1 : e;
            int vn = srcs[en];
            u32 pn = hin32[(size_t)vn * 64 + lane];
            float v0 = fmaxf(blo(p), 0.f) + 1e-7f;
            float v1 = fmaxf(bhi(p), 0.f) + 1e-7f;
            float l0 = v0 * t, l1 = v1 * t;
            mx = fmaxf(mx, fmaxf(l0, l1));
            mv = fmaxf(mv, fmaxf(v0, v1));
            float w0 = __expf(l0), w1 = __expf(l1);
            s0 += w0; s1 += w1;
            sn0 = fmaf(w0, v0, sn0);
            sn1 = fmaf(w1, v1, sn1);
            p = pn;
        }
    }

    bool has = (end > beg);
    if (__any(has && (mx > 60.f || mx < -20.f || mv > 1.0e10f))) {
        // exact online-softmax fallback (rare; correct for any t / magnitudes)
        float m0 = -3.0e38f, m1 = -3.0e38f;
        s0 = s1 = sn0 = sn1 = 0.f;
        for (int e = beg; e < end; ++e) {
            int v = srcs[e];
            u32 p = hin32[(size_t)v * 64 + lane];
            float v0 = fmaxf(blo(p), 0.f) + 1e-7f;
            float v1 = fmaxf(bhi(p), 0.f) + 1e-7f;
            float l0 = v0 * t, l1 = v1 * t;
            float nm0 = fmaxf(m0, l0), nm1 = fmaxf(m1, l1);
            float a0 = __expf(m0 - nm0), a1 = __expf(m1 - nm1);
            float w0 = __expf(l0 - nm0), w1 = __expf(l1 - nm1);
            s0 = s0 * a0 + w0;           s1 = s1 * a1 + w1;
            sn0 = sn0 * a0 + w0 * v0;    sn1 = sn1 * a1 + w1 * v1;
            m0 = nm0; m1 = nm1;
        }
    }

    float aggr0 = sn0 / (s0 + 1e-16f);
    float aggr1 = sn1 / (s1 + 1e-16f);
    u32 pu = hin32[(size_t)u * 64 + lane];
    float o0 = aggr0 + blo(pu);
    float o1 = aggr1 + bhi(pu);
    ((u32*)g)[(size_t)u * 64 + lane] = (u32)f2b(o0) | ((u32)f2b(o1) << 16);
}

// ---------------- mm1: h1 = g @ W1 (bf16 MFMA), fused BN partials ----------------
// 128x128 tile, 256 threads (4 waves), BK=64 chunks, K=128.

__global__ __launch_bounds__(256) void k_mm1(const u16* __restrict__ A,
                                             const u16* __restrict__ WT,
                                             u16* __restrict__ C,
                                             float* __restrict__ bnsum,
                                             float* __restrict__ bnss, int M) {
    __shared__ u16 As[128][72];   // stride 144B: 2-way bank alias (free)
    __shared__ u16 Bs[128][72];
    __shared__ float csum[128], css[128];
    int row0 = blockIdx.x * 128, n0 = blockIdx.y * 128;
    int tid = threadIdx.x;
    int lane = tid & 63, w = tid >> 6;
    int r0w = (w & 1) * 64, c0w = (w >> 1) * 64;
    int q = lane >> 4, ml = lane & 15;

    if (tid < 128) { csum[tid] = 0.f; css[tid] = 0.f; }

    f32x4 acc[4][4];
    #pragma unroll
    for (int i = 0; i < 4; ++i)
        #pragma unroll
        for (int j = 0; j < 4; ++j) acc[i][j] = f32x4{0.f, 0.f, 0.f, 0.f};

    for (int kk = 0; kk < 128; kk += 64) {
        #pragma unroll
        for (int i = 0; i < 4; ++i) {
            int r = i * 32 + (tid >> 3);
            int c8 = (tid & 7) * 8;
            s16x8 va = s16x8{0, 0, 0, 0, 0, 0, 0, 0};
            if (row0 + r < M)
                va = *reinterpret_cast<const s16x8*>(&A[(size_t)(row0 + r) * 128 + kk + c8]);
            *reinterpret_cast<s16x8*>(&As[r][c8]) = va;
            s16x8 vb = *reinterpret_cast<const s16x8*>(&WT[(size_t)(n0 + r) * 128 + kk + c8]);
            *reinterpret_cast<s16x8*>(&Bs[r][c8]) = vb;
        }
        __syncthreads();
        #pragma unroll
        for (int ks = 0; ks < 64; ks += 32) {
            s16x8 af[4], bfr[4];
            #pragma unroll
            for (int rt = 0; rt < 4; ++rt)
                af[rt] = *reinterpret_cast<const s16x8*>(&As[r0w + rt * 16 + ml][ks + q * 8]);
            #pragma unroll
            for (int ct = 0; ct < 4; ++ct)
                bfr[ct] = *reinterpret_cast<const s16x8*>(&Bs[c0w + ct * 16 + ml][ks + q * 8]);
            #pragma unroll
            for (int rt = 0; rt < 4; ++rt)
                #pragma unroll
                for (int ct = 0; ct < 4; ++ct)
                    acc[rt][ct] = __builtin_amdgcn_mfma_f32_16x16x32_bf16(
                        af[rt], bfr[ct], acc[rt][ct], 0, 0, 0);
        }
        __syncthreads();
    }

    #pragma unroll
    for (int ct = 0; ct < 4; ++ct) {
        float s = 0.f, ss = 0.f;
        int col = n0 + c0w + ct * 16 + ml;
        #pragma unroll
        for (int rt = 0; rt < 4; ++rt) {
            int rbase = row0 + r0w + rt * 16 + q * 4;
            #pragma unroll
            for (int rg = 0; rg < 4; ++rg) {
                float v = acc[rt][ct][rg];
                s += v;
                ss += v * v;
                if (rbase + rg < M)
                    C[(size_t)(rbase + rg) * H + col] = f2b(v);
            }
        }
        atomicAdd(&csum[c0w + ct * 16 + ml], s);
        atomicAdd(&css[c0w + ct * 16 + ml], ss);
    }
    __syncthreads();
    if (tid < 128) {
        atomicAdd(&bnsum[n0 + tid], csum[tid]);
        atomicAdd(&bnss[n0 + tid], css[tid]);
    }
}

// ---------------- BN finalize ----------------

__global__ __launch_bounds__(256) void k_bnfin(const float* __restrict__ bnsum,
                                               const float* __restrict__ bnss,
                                               const float* __restrict__ gamma,
                                               const float* __restrict__ beta,
                                               float* __restrict__ scale,
                                               float* __restrict__ shift, int M) {
    int c = threadIdx.x;
    float inv = 1.0f / (float)M;
    float mean = bnsum[c] * inv;
    float var = bnss[c] * inv - mean * mean;
    if (var < 0.f) var = 0.f;
    float rstd = rsqrtf(var + 1e-5f);
    float sc = rstd * gamma[c];
    scale[c] = sc;
    shift[c] = beta[c] - mean * sc;
}

// ---------------- mm2: out = relu(norm(h1)) @ W2 (norm fused in A-stage) ----------------

__global__ __launch_bounds__(256) void k_mm2(const u16* __restrict__ H1,
                                             const float* __restrict__ scale,
                                             const float* __restrict__ shift,
                                             const u16* __restrict__ WT,
                                             float* __restrict__ outf,
                                             u16* __restrict__ outb, int M) {
    __shared__ u16 As[128][72];
    __shared__ u16 Bs[128][72];
    int row0 = blockIdx.x * 128;
    int tid = threadIdx.x;
    int lane = tid & 63, w = tid >> 6;
    int r0w = (w & 1) * 64, c0w = (w >> 1) * 64;
    int q = lane >> 4, ml = lane & 15;

    f32x4 acc[4][4];
    #pragma unroll
    for (int i = 0; i < 4; ++i)
        #pragma unroll
        for (int j = 0; j < 4; ++j) acc[i][j] = f32x4{0.f, 0.f, 0.f, 0.f};

    for (int kk = 0; kk < 256; kk += 64) {
        #pragma unroll
        for (int i = 0; i < 4; ++i) {
            int r = i * 32 + (tid >> 3);
            int c8 = (tid & 7) * 8;
            s16x8 o = s16x8{0, 0, 0, 0, 0, 0, 0, 0};
            if (row0 + r < M) {
                s16x8 v = *reinterpret_cast<const s16x8*>(&H1[(size_t)(row0 + r) * H + kk + c8]);
                #pragma unroll
                for (int j = 0; j < 8; ++j) {
                    float f = b2f((u16)v[j]) * scale[kk + c8 + j] + shift[kk + c8 + j];
                    o[j] = (short)f2b(fmaxf(f, 0.f));
                }
            }
            *reinterpret_cast<s16x8*>(&As[r][c8]) = o;
            s16x8 vb = *reinterpret_cast<const s16x8*>(&WT[(size_t)r * H + kk + c8]);
            *reinterpret_cast<s16x8*>(&Bs[r][c8]) = vb;
        }
        __syncthreads();
        #pragma unroll
        for (int ks = 0; ks < 64; ks += 32) {
            s16x8 af[4], bfr[4];
            #pragma unroll
            for (int rt = 0; rt < 4; ++rt)
                af[rt] = *reinterpret_cast<const s16x8*>(&As[r0w + rt * 16 + ml][ks + q * 8]);
            #pragma unroll
            for (int ct = 0; ct < 4; ++ct)
                bfr[ct] = *reinterpret_cast<const s16x8*>(&Bs[c0w + ct * 16 + ml][ks + q * 8]);
            #pragma unroll
            for (int rt = 0; rt < 4; ++rt)
                #pragma unroll
                for (int ct = 0; ct < 4; ++ct)
                    acc[rt][ct] = __builtin_amdgcn_mfma_f32_16x16x32_bf16(
                        af[rt], bfr[ct], acc[rt][ct], 0, 0, 0);
        }
        __syncthreads();
    }

    #pragma unroll
    for (int ct = 0; ct < 4; ++ct) {
        int col = c0w + ct * 16 + ml;
        #pragma unroll
        for (int rt = 0; rt < 4; ++rt) {
            int rbase = row0 + r0w + rt * 16 + q * 4;
            #pragma unroll
            for (int rg = 0; rg < 4; ++rg) {
                if (rbase + rg < M) {
                    float v = acc[rt][ct][rg];
                    if (outb)
                        outb[(size_t)(rbase + rg) * D + col] = f2b(fmaxf(v, 0.f));
                    else
                        outf[(size_t)(rbase + rg) * D + col] = v;
                }
            }
        }
    }
}

// ---------------- host launch ----------------

extern "C" void kernel_launch(void* const* d_in, const int* in_sizes, int n_in,
                              void* d_out, int out_size, void* d_ws, size_t ws_size,
                              hipStream_t stream) {
    const float* x         = (const float*)d_in[0];
    const int*   ei        = (const int*)d_in[1];
    const float* t_all     = (const float*)d_in[2];
    const float* W1_all    = (const float*)d_in[3];
    const float* W2_all    = (const float*)d_in[4];
    const float* gamma_all = (const float*)d_in[5];
    const float* beta_all  = (const float*)d_in[6];

    int N = in_sizes[0] / D;
    int E = in_sizes[1] / 2;
    float* out = (float*)d_out;

    char* ws = (char*)d_ws;
    size_t off = 0;
    auto alloc = [&](size_t bytes) -> void* {
        void* p = ws + off;
        off += (bytes + 255) & ~(size_t)255;
        return p;
    };
    int* rowptr = (int*)alloc((size_t)(N + 1) * 4);
    int* deg    = (int*)alloc((size_t)N * 4);
    int* srcs   = (int*)alloc((size_t)E * 4);
    u16* xb     = (u16*)alloc((size_t)N * D * 2);
    u16* a0     = (u16*)alloc((size_t)N * D * 2);
    u16* a1     = (u16*)alloc((size_t)N * D * 2);
    u16* g      = (u16*)alloc((size_t)N * D * 2);
    u16* h1     = (u16*)alloc((size_t)N * H * 2);
    u16* WT1    = (u16*)alloc((size_t)4 * H * D * 2);
    u16* WT2    = (u16*)alloc((size_t)4 * D * H * 2);
    float* bnsum = (float*)alloc(H * 4);
    float* bnss  = (float*)alloc(H * 4);
    float* scale = (float*)alloc(H * 4);
    float* shift = (float*)alloc(H * 4);
    (void)ws_size; (void)n_in; (void)out_size;

    const int* srcA = ei;
    const int* dstA = ei + E;

    // prep: bf16 casts + weight transposes
    k_cvt<<<(N * D / 4 + 255) / 256, 256, 0, stream>>>(x, xb, N * D / 4);
    k_prep<<<1024, 256, 0, stream>>>(W1_all, W2_all, WT1, WT2);

    // CSR build
    hipMemsetAsync(deg, 0, (size_t)N * 4, stream);
    k_count<<<(E + 255) / 256, 256, 0, stream>>>(dstA, deg, E);
    k_scan<<<1, 1024, 0, stream>>>(deg, rowptr, N);
    hipMemsetAsync(deg, 0, (size_t)N * 4, stream);
    k_scatter<<<(E + 255) / 256, 256, 0, stream>>>(srcA, dstA, rowptr, deg, srcs, E);

    float* out0 = out;                  // mu
    float* out1 = out + (size_t)N * D;  // logstd

    int gx = (N + 127) / 128;
    for (int layer = 0; layer < 4; ++layer) {
        const u16* hin = (layer == 0) ? xb : (layer == 1 ? a0 : a1);
        k_edge<<<(N + 3) / 4, 256, 0, stream>>>(hin, rowptr, srcs, t_all + layer,
                                                g, bnsum, bnss, N);

        k_mm1<<<dim3(gx, 2), 256, 0, stream>>>(g, WT1 + (size_t)layer * H * D, h1,
                                               bnsum, bnss, N);
        k_bnfin<<<1, H, 0, stream>>>(bnsum, bnss, gamma_all + (size_t)layer * H,
                                     beta_all + (size_t)layer * H, scale, shift, N);

        float* outf = nullptr;
        u16*   outb = nullptr;
        if (layer == 0)      outb = a0;
        else if (layer == 1) outb = a1;
        else if (layer == 2) outf = out0;
        else                 outf = out1;

        k_mm2<<<dim3(gx, 1), 256, 0, stream>>>(h1, scale, shift,
                                               WT2 + (size_t)layer * D * H,
                                               outf, outb, N);
    }
}